// Round 1
// baseline (326.376 us; speedup 1.0000x reference)
//
#include <hip/hip_runtime.h>

#define FDIM 64

__global__ void dmpnn_scatter_add(const float* __restrict__ edges,
                                  const int* __restrict__ recv,   // edge_index row 0
                                  float* __restrict__ pooled,
                                  long long total /* = M * FDIM */) {
    long long tid = (long long)blockIdx.x * blockDim.x + threadIdx.x;
    if (tid >= total) return;
    int e = (int)(tid >> 6);
    int f = (int)(tid & 63);
    float v = edges[tid];
    int node = recv[e];
    atomicAdd(&pooled[(long long)node * FDIM + f], v);
}

__global__ void dmpnn_gather_sub(const float* __restrict__ pooled,
                                 const float* __restrict__ edges,
                                 const int* __restrict__ send,    // edge_index row 1
                                 const int* __restrict__ pair,    // edge_pairs row 0
                                 float* __restrict__ out,
                                 long long total /* = M * FDIM/4 */) {
    long long tid = (long long)blockIdx.x * blockDim.x + threadIdx.x;
    if (tid >= total) return;
    int e = (int)(tid >> 4);   // 16 float4 quads per edge row
    int q = (int)(tid & 15);
    int sn = send[e];
    int pe = pair[e];
    float4 a = *reinterpret_cast<const float4*>(&pooled[(long long)sn * FDIM + q * 4]);
    float4 b = *reinterpret_cast<const float4*>(&edges[(long long)pe * FDIM + q * 4]);
    float4 r;
    r.x = a.x - b.x;
    r.y = a.y - b.y;
    r.z = a.z - b.z;
    r.w = a.w - b.w;
    *reinterpret_cast<float4*>(&out[tid * 4]) = r;
}

extern "C" void kernel_launch(void* const* d_in, const int* in_sizes, int n_in,
                              void* d_out, int out_size, void* d_ws, size_t ws_size,
                              hipStream_t stream) {
    const float* edges      = (const float*)d_in[1];
    const int*   edge_index = (const int*)d_in[2];   // [2, M] flat
    const int*   edge_pairs = (const int*)d_in[3];   // [1, M] flat

    const int N = in_sizes[0] / FDIM;   // 50000
    const int M = in_sizes[1] / FDIM;   // 1000000

    float* pooled = (float*)d_ws;       // N * FDIM floats = 12.8 MB

    // Zero the scatter accumulator every call (deterministic across replays).
    hipMemsetAsync(pooled, 0, (size_t)N * FDIM * sizeof(float), stream);

    // Pass 1: scatter-sum edges into pooled.
    {
        long long total = (long long)M * FDIM;
        int blk = 256;
        long long grid = (total + blk - 1) / blk;
        dmpnn_scatter_add<<<dim3((unsigned)grid), dim3(blk), 0, stream>>>(
            edges, edge_index, pooled, total);
    }

    // Pass 2: out[e] = pooled[edge_index[1][e]] - edges[edge_pairs[0][e]].
    {
        long long total = (long long)M * (FDIM / 4);
        int blk = 256;
        long long grid = (total + blk - 1) / blk;
        dmpnn_gather_sub<<<dim3((unsigned)grid), dim3(blk), 0, stream>>>(
            pooled, edges, edge_index + M, edge_pairs, (float*)d_out, total);
    }
}